// Round 4
// baseline (1358.196 us; speedup 1.0000x reference)
//
#include <hip/hip_runtime.h>
#include <hip/hip_bf16.h>

// ---------------------------------------------------------------------------
// GNN forward on MI355X, round 4: register-resident activation chain.
//
// Core trick: with MFMA operand order mfma(W, X, acc) (HW-verified r2/r3),
// apply a k-permutation perm(k) = ((k&7)>>2)*16 + (k>>3)*4 + (k&3) to BOTH
// the W fragment layout and the X fragment layout. perm is a bijection on
// 0..31, so each 32-wide dot product is unchanged — but now the D-tile
// register layout IS the next layer's X-fragment layout:
//     xfrag[i][kt] elem j  =  acc[i][2*kt + (j>>2)][j&3]
// => inter-layer handoff is pure register renaming. No LDS activation
// round-trip, no cross-lane ops, and NO BARRIERS in the entire kernel.
//
// Each wave owns 32 rows end-to-end: gather -> redux MLP -> (in-kernel
// embed for base) -> node MLP -> store. Residual a_{n-1} lives in
// wave-private LDS as exact f32. Grid = 1024 fully-independent waves.
// ---------------------------------------------------------------------------

#define H        128
#define FEAT     32
#define M_NODES  32768
#define L_LAYERS 16
#define MU_      (M_NODES / 2)

typedef __bf16 bf16x8 __attribute__((ext_vector_type(8)));
typedef float  f32x4  __attribute__((ext_vector_type(4)));

#define MFMA_BF16 __builtin_amdgcn_mfma_f32_16x16x32_bf16

// frag-pair slots in d_ws: 2 KB each (1 KB hi plane, 1 KB lo plane).
// frag (c,kt): lane l elem j holds W[c*16 + (l&15)][kt*32 + perm((l>>4)*8+j)]
#define SLOT_EMB    0                  // K=32,  KT=1, 8 fps
#define SLOT_MPU(l) (8 + (l) * 32)     // K=128, KT=4, 5 layers
#define SLOT_MPB0   168                // K=256, KT=8
#define SLOT_MPB(l) (232 + (l) * 32)
#define SLOT_NE0    360                // K=256, KT=8
#define SLOT_NE(l)  (424 + (l) * 32)
#define TOTAL_FP    552

// ---------------------------------------------------------------------------
__global__ void prep_kernel(__bf16* __restrict__ frags,
                            const float* __restrict__ emb_w,
                            const float* __restrict__ mpu_w,
                            const float* __restrict__ mpb0_w,
                            const float* __restrict__ mpb_w,
                            const float* __restrict__ ne0_w,
                            const float* __restrict__ ne_w) {
  int fp = blockIdx.x * 4 + (threadIdx.x >> 6);
  if (fp >= TOTAL_FP) return;
  int lane = threadIdx.x & 63;
  int r16 = lane & 15, g = lane >> 4;
  const float* src; int K; int idx;
  if (fp < 8)        { src = emb_w;                             K = 32;  idx = fp; }
  else if (fp < 168) { src = mpu_w + ((fp - 8) >> 5) * H * H;   K = 128; idx = (fp - 8) & 31; }
  else if (fp < 232) { src = mpb0_w;                            K = 256; idx = fp - 168; }
  else if (fp < 360) { src = mpb_w + ((fp - 232) >> 5) * H * H; K = 128; idx = (fp - 232) & 31; }
  else if (fp < 424) { src = ne0_w;                             K = 256; idx = fp - 360; }
  else               { src = ne_w + ((fp - 424) >> 5) * H * H;  K = 128; idx = (fp - 424) & 31; }
  int KT = K >> 5;
  int c = idx / KT, kt = idx - c * KT;
  int col = c * 16 + r16;
  __bf16* dhi = frags + ((size_t)fp << 10) + lane * 8;
#pragma unroll
  for (int j = 0; j < 8; ++j) {
    int k = kt * 32 + ((j >> 2) * 16 + g * 4 + (j & 3));   // permuted k slot
    float x  = src[col * K + k];
    __bf16 h = (__bf16)x;
    dhi[j]       = h;
    dhi[512 + j] = (__bf16)(x - (float)h);
  }
}

// ---------------------------------------------------------------------------
__device__ __forceinline__ void split_pair(const f32x4& a, const f32x4& b,
                                           bf16x8& h, bf16x8& l) {
#pragma unroll
  for (int j = 0; j < 4; ++j) {
    __bf16 t = (__bf16)a[j]; h[j] = t;     l[j] = (__bf16)(a[j] - (float)t);
    __bf16 u = (__bf16)b[j]; h[4 + j] = u; l[4 + j] = (__bf16)(b[j] - (float)u);
  }
}

__device__ __forceinline__ void zero_acc8(f32x4 (&acc)[2][8]) {
  f32x4 z = {0.f, 0.f, 0.f, 0.f};
#pragma unroll
  for (int i = 0; i < 2; ++i)
#pragma unroll
    for (int c = 0; c < 8; ++c) acc[i][c] = z;
}

// Build X frags (permuted layout) for a K=128 slab from two global f32 rows.
__device__ __forceinline__ void gather_frags128(bf16x8 (&xh)[2][4], bf16x8 (&xl)[2][4],
                                                const float* __restrict__ s0,
                                                const float* __restrict__ s1, int g) {
#pragma unroll
  for (int i = 0; i < 2; ++i) {
    const float* src = i ? s1 : s0;
#pragma unroll
    for (int kt = 0; kt < 4; ++kt) {
      f32x4 a = *(const f32x4*)(src + kt * 32 + g * 4);
      f32x4 b = *(const f32x4*)(src + kt * 32 + 16 + g * 4);
      split_pair(a, b, xh[i][kt], xl[i][kt]);
    }
  }
}

// acc += split3( X(32 rows) @ W^T ), K=128 pass. W streamed from L2.
__device__ __forceinline__ void stage128(f32x4 (&acc)[2][8],
                                         const bf16x8 (&xh)[2][4], const bf16x8 (&xl)[2][4],
                                         const __bf16* __restrict__ frags,
                                         int fp0, int KT, int kt0, int lane) {
#pragma unroll
  for (int cp = 0; cp < 4; ++cp) {
    const int c0 = 2 * cp, c1 = 2 * cp + 1;
#pragma unroll
    for (int kt = 0; kt < 4; ++kt) {
      const __bf16* f0 = frags + (((size_t)(fp0 + c0 * KT + kt0 + kt)) << 10) + lane * 8;
      const __bf16* f1 = frags + (((size_t)(fp0 + c1 * KT + kt0 + kt)) << 10) + lane * 8;
      bf16x8 w0h = *(const bf16x8*)f0;
      bf16x8 w0l = *(const bf16x8*)(f0 + 512);
      bf16x8 w1h = *(const bf16x8*)f1;
      bf16x8 w1l = *(const bf16x8*)(f1 + 512);
      // 12 MFMAs, same-acc revisit distance 4
      acc[0][c0] = MFMA_BF16(w0h, xh[0][kt], acc[0][c0], 0, 0, 0);
      acc[0][c1] = MFMA_BF16(w1h, xh[0][kt], acc[0][c1], 0, 0, 0);
      acc[1][c0] = MFMA_BF16(w0h, xh[1][kt], acc[1][c0], 0, 0, 0);
      acc[1][c1] = MFMA_BF16(w1h, xh[1][kt], acc[1][c1], 0, 0, 0);
      acc[0][c0] = MFMA_BF16(w0l, xh[0][kt], acc[0][c0], 0, 0, 0);
      acc[0][c1] = MFMA_BF16(w1l, xh[0][kt], acc[0][c1], 0, 0, 0);
      acc[1][c0] = MFMA_BF16(w0l, xh[1][kt], acc[1][c0], 0, 0, 0);
      acc[1][c1] = MFMA_BF16(w1l, xh[1][kt], acc[1][c1], 0, 0, 0);
      acc[0][c0] = MFMA_BF16(w0h, xl[0][kt], acc[0][c0], 0, 0, 0);
      acc[0][c1] = MFMA_BF16(w1h, xl[0][kt], acc[0][c1], 0, 0, 0);
      acc[1][c0] = MFMA_BF16(w0h, xl[1][kt], acc[1][c0], 0, 0, 0);
      acc[1][c1] = MFMA_BF16(w1h, xl[1][kt], acc[1][c1], 0, 0, 0);
    }
  }
}

// K=32 pass for the embedding (one k-tile).
__device__ __forceinline__ void stage32(f32x4 (&acc)[2][8],
                                        const bf16x8 (&fh)[2], const bf16x8 (&fl)[2],
                                        const __bf16* __restrict__ frags, int fp0, int lane) {
#pragma unroll
  for (int cp = 0; cp < 4; ++cp) {
    const int c0 = 2 * cp, c1 = 2 * cp + 1;
    const __bf16* f0 = frags + (((size_t)(fp0 + c0)) << 10) + lane * 8;
    const __bf16* f1 = frags + (((size_t)(fp0 + c1)) << 10) + lane * 8;
    bf16x8 w0h = *(const bf16x8*)f0;
    bf16x8 w0l = *(const bf16x8*)(f0 + 512);
    bf16x8 w1h = *(const bf16x8*)f1;
    bf16x8 w1l = *(const bf16x8*)(f1 + 512);
    acc[0][c0] = MFMA_BF16(w0h, fh[0], acc[0][c0], 0, 0, 0);
    acc[0][c1] = MFMA_BF16(w1h, fh[0], acc[0][c1], 0, 0, 0);
    acc[1][c0] = MFMA_BF16(w0h, fh[1], acc[1][c0], 0, 0, 0);
    acc[1][c1] = MFMA_BF16(w1h, fh[1], acc[1][c1], 0, 0, 0);
    acc[0][c0] = MFMA_BF16(w0l, fh[0], acc[0][c0], 0, 0, 0);
    acc[0][c1] = MFMA_BF16(w1l, fh[0], acc[0][c1], 0, 0, 0);
    acc[1][c0] = MFMA_BF16(w0l, fh[1], acc[1][c0], 0, 0, 0);
    acc[1][c1] = MFMA_BF16(w1l, fh[1], acc[1][c1], 0, 0, 0);
    acc[0][c0] = MFMA_BF16(w0h, fl[0], acc[0][c0], 0, 0, 0);
    acc[0][c1] = MFMA_BF16(w1h, fl[0], acc[0][c1], 0, 0, 0);
    acc[1][c0] = MFMA_BF16(w0h, fl[1], acc[1][c0], 0, 0, 0);
    acc[1][c1] = MFMA_BF16(w1h, fl[1], acc[1][c1], 0, 0, 0);
  }
}

// relu(acc + bias) -> next-layer frags, with residual bookkeeping in
// wave-private LDS (pv). PM: 0 = write prev only (L0); 1 = x += prev, write
// prev (L1..L3); 2 = frags only (L4 / embed).
template <int PM>
__device__ __forceinline__ void epilogue_frags(const f32x4 (&acc)[2][8],
                                               const float* __restrict__ bias,
                                               float* pv, int g,
                                               bf16x8 (&xh)[2][4], bf16x8 (&xl)[2][4]) {
#pragma unroll
  for (int i = 0; i < 2; ++i)
#pragma unroll
    for (int kt = 0; kt < 4; ++kt) {
      f32x4 x0, x1;
#pragma unroll
      for (int hf = 0; hf < 2; ++hf) {
        const int c = 2 * kt + hf;
        f32x4 bv = *(const f32x4*)(bias + c * 16 + g * 4);
        f32x4 a, x;
#pragma unroll
        for (int j = 0; j < 4; ++j) a[j] = fmaxf(acc[i][c][j] + bv[j], 0.f);
        x = a;
        if (PM == 1) {
          f32x4 p = *(const f32x4*)(pv + (i * 8 + c) * 256);
#pragma unroll
          for (int j = 0; j < 4; ++j) x[j] = a[j] + p[j];
        }
        if (PM != 2) *(f32x4*)(pv + (i * 8 + c) * 256) = a;
        if (hf == 0) x0 = x; else x1 = x;
      }
      split_pair(x0, x1, xh[i][kt], xl[i][kt]);
    }
}

__device__ __forceinline__ void epilogue_store(const f32x4 (&acc)[2][8],
                                               const float* __restrict__ bias,
                                               float* __restrict__ out, int r16, int g) {
#pragma unroll
  for (int i = 0; i < 2; ++i)
#pragma unroll
    for (int c = 0; c < 8; ++c) {
      f32x4 bv = *(const f32x4*)(bias + c * 16 + g * 4);
      f32x4 v;
#pragma unroll
      for (int j = 0; j < 4; ++j) v[j] = fmaxf(acc[i][c][j] + bv[j], 0.f);
      *(f32x4*)(out + (size_t)(i * 16 + r16) * H + c * 16 + g * 4) = v;
    }
}

// Build feats frags (K=32) for rows row_a, row_b of node_feats.
__device__ __forceinline__ void feats_frags(bf16x8 (&fh)[2], bf16x8 (&fl)[2],
                                            const float* __restrict__ feats,
                                            int row_a, int row_b, int g) {
#pragma unroll
  for (int i = 0; i < 2; ++i) {
    const float* src = feats + (size_t)(i ? row_b : row_a) * FEAT;
    f32x4 a = *(const f32x4*)(src + g * 4);
    f32x4 b = *(const f32x4*)(src + 16 + g * 4);
    split_pair(a, b, fh[i], fl[i]);
  }
}

// ---------------------------------------------------------------------------
__global__ __launch_bounds__(256, 1) void base0_kernel(float* __restrict__ E,
                                                       const float* __restrict__ feats,
                                                       const __bf16* __restrict__ frags,
                                                       const float* __restrict__ emb_b) {
  int tid = threadIdx.x, lane = tid & 63, wave = tid >> 6;
  int r16 = lane & 15, g = lane >> 4;
  int R0 = blockIdx.x * 128 + wave * 32;
  bf16x8 fh[2], fl[2];
  feats_frags(fh, fl, feats, R0 + r16, R0 + 16 + r16, g);
  f32x4 acc[2][8];
  zero_acc8(acc);
  stage32(acc, fh, fl, frags, SLOT_EMB, lane);
  epilogue_store(acc, emb_b, E + (size_t)R0 * H, r16, g);
}

// ---------------------------------------------------------------------------
__global__ __launch_bounds__(256, 1) void phase_kernel(
    float* __restrict__ E, const int* __restrict__ parents,
    const __bf16* __restrict__ frags, const float* __restrict__ feats,
    const float* __restrict__ emb_b,
    const float* __restrict__ mpu_b, const float* __restrict__ mpb0_b,
    const float* __restrict__ mpb_b, const float* __restrict__ ne0_b,
    const float* __restrict__ ne_b, int s) {
  __shared__ float prevb[4 * 4096];           // 16 KB per wave, wave-private
  int tid = threadIdx.x, lane = tid & 63, wave = tid >> 6;
  int r16 = lane & 15, g = lane >> 4;
  int R0 = blockIdx.x * 128 + wave * 32;
  float* pv = prevb + wave * 4096 + lane * 4;
  int gr_a = s + R0 + r16;
  int gr_b = gr_a + 16;

  f32x4 acc[2][8];
  bf16x8 xh[2][4], xl[2][4];

  // ---- redux chain ----
  if (R0 < MU_) {
    // unary: msg = E[parents[gr][0]], 5 x K=128 linears (mpu)
    int pa = parents[2 * gr_a], pb = parents[2 * gr_b];
    gather_frags128(xh, xl, E + (size_t)pa * H, E + (size_t)pb * H, g);
    zero_acc8(acc);
    stage128(acc, xh, xl, frags, SLOT_MPU(0), 4, 0, lane);
    epilogue_frags<0>(acc, mpu_b, pv, g, xh, xl);
    for (int l = 1; l <= 3; ++l) {
      zero_acc8(acc);
      stage128(acc, xh, xl, frags, SLOT_MPU(l), 4, 0, lane);
      epilogue_frags<1>(acc, mpu_b + l * H, pv, g, xh, xl);
    }
    zero_acc8(acc);
    stage128(acc, xh, xl, frags, SLOT_MPU(4), 4, 0, lane);
    epilogue_frags<2>(acc, mpu_b + 4 * H, pv, g, xh, xl);
  } else {
    // binary: msg = [E[p0] | E[p1]], L0 K=256 (mpb0) then 4 x K=128 (mpb)
    int p0a = parents[2 * gr_a], p1a = parents[2 * gr_a + 1];
    int p0b = parents[2 * gr_b], p1b = parents[2 * gr_b + 1];
    gather_frags128(xh, xl, E + (size_t)p0a * H, E + (size_t)p0b * H, g);
    zero_acc8(acc);
    stage128(acc, xh, xl, frags, SLOT_MPB0, 8, 0, lane);   // k 0..127
    gather_frags128(xh, xl, E + (size_t)p1a * H, E + (size_t)p1b * H, g);
    stage128(acc, xh, xl, frags, SLOT_MPB0, 8, 4, lane);   // k 128..255
    epilogue_frags<0>(acc, mpb0_b, pv, g, xh, xl);
    for (int l = 0; l <= 2; ++l) {
      zero_acc8(acc);
      stage128(acc, xh, xl, frags, SLOT_MPB(l), 4, 0, lane);
      epilogue_frags<1>(acc, mpb_b + l * H, pv, g, xh, xl);
    }
    zero_acc8(acc);
    stage128(acc, xh, xl, frags, SLOT_MPB(3), 4, 0, lane);
    epilogue_frags<2>(acc, mpb_b + 3 * H, pv, g, xh, xl);
  }

  // ---- node chain: x = [base | redux], L0 K=256 (ne0) then 4 x K=128 (ne)
  // xh/xl currently hold the redux frags -> consume them first (k 128..255)
  zero_acc8(acc);
  stage128(acc, xh, xl, frags, SLOT_NE0, 8, 4, lane);
  // base = relu(emb(feats rows)) computed in-register (embed kernel fused)
  {
    bf16x8 fh[2], fl[2];
    feats_frags(fh, fl, feats, gr_a, gr_b, g);
    f32x4 acc2[2][8];
    zero_acc8(acc2);
    stage32(acc2, fh, fl, frags, SLOT_EMB, lane);
    epilogue_frags<2>(acc2, emb_b, pv, g, xh, xl);   // xh/xl <- base frags
  }
  stage128(acc, xh, xl, frags, SLOT_NE0, 8, 0, lane);  // k 0..127 (base)
  epilogue_frags<0>(acc, ne0_b, pv, g, xh, xl);
  for (int l = 0; l <= 2; ++l) {
    zero_acc8(acc);
    stage128(acc, xh, xl, frags, SLOT_NE(l), 4, 0, lane);
    epilogue_frags<1>(acc, ne_b + l * H, pv, g, xh, xl);
  }
  zero_acc8(acc);
  stage128(acc, xh, xl, frags, SLOT_NE(3), 4, 0, lane);
  epilogue_store(acc, ne_b + 3 * H, E + (size_t)(s + R0) * H, r16, g);
}

// ---------------------------------------------------------------------------
extern "C" void kernel_launch(void* const* d_in, const int* in_sizes, int n_in,
                              void* d_out, int out_size, void* d_ws, size_t ws_size,
                              hipStream_t stream) {
  const float* node_feats = (const float*)d_in[0];
  const float* emb_w  = (const float*)d_in[1];
  const float* emb_b  = (const float*)d_in[2];
  const float* ne0_w  = (const float*)d_in[3];
  const float* ne0_b  = (const float*)d_in[4];
  const float* ne_w   = (const float*)d_in[5];
  const float* ne_b   = (const float*)d_in[6];
  const float* mpu_w  = (const float*)d_in[7];
  const float* mpu_b  = (const float*)d_in[8];
  const float* mpb0_w = (const float*)d_in[9];
  const float* mpb0_b = (const float*)d_in[10];
  const float* mpb_w  = (const float*)d_in[11];
  const float* mpb_b  = (const float*)d_in[12];
  const int*   parents = (const int*)d_in[13];
  float* E = (float*)d_out;
  __bf16* frags = (__bf16*)d_ws;   // 552 * 2048 B ~= 1.13 MB

  prep_kernel<<<(TOTAL_FP + 3) / 4, 256, 0, stream>>>(frags, emb_w, mpu_w, mpb0_w,
                                                      mpb_w, ne0_w, ne_w);
  base0_kernel<<<M_NODES / 128, 256, 0, stream>>>(E, node_feats, frags, emb_b);
  for (int l = 1; l < L_LAYERS; ++l) {
    phase_kernel<<<M_NODES / 128, 256, 0, stream>>>(E, parents, frags, node_feats,
                                                    emb_b, mpu_b, mpb0_b, mpb_b,
                                                    ne0_b, ne_b, l * M_NODES);
  }
}